// Round 1
// baseline (39.093 us; speedup 1.0000x reference)
//
#include <hip/hip_runtime.h>

// GaussianSpot: out[k,b,i,j] = height[k,b] * (1/(2*pi*w^2)) * exp(-0.5*((i-sx)^2+(j-sy)^2)/w^2)
// where (sx,sy) = target_locs[n_idx[b], f_idx[b]] + (x[k,b], y[k,b]).
// Shapes: K=2, B=100000, N=1000, F=500, D=14. Output [K,B,D,D] f32 = 39.2M elems.
// Memory-bound: 156.8 MB streamed write; inputs (~8 MB) are cache-resident.

#define KB_TOTAL 200000u      // K*B spots
#define B_NUM    100000u
#define F_NUM    500
#define D_DIM    14u
#define F4_PER_SPOT 49u       // 196 pixels / 4
#define TOTAL_F4 (KB_TOTAL * F4_PER_SPOT)  // 9,800,000 float4 stores

__global__ __launch_bounds__(256) void gspot_kernel(
    const float* __restrict__ height,
    const float* __restrict__ width,
    const float* __restrict__ xoff,
    const float* __restrict__ yoff,
    const float* __restrict__ tlocs,   // [N, F, 2]
    const int*   __restrict__ n_idx,   // [B]
    const int*   __restrict__ f_idx,   // [B]
    float4*      __restrict__ out)
{
    const float HALF_LOG2E = 0.7213475204444817f;   // 0.5 * log2(e)
    const float INV_2PI    = 0.15915494309189535f;  // 1 / (2*pi)

    unsigned stride = gridDim.x * blockDim.x;
    for (unsigned t = blockIdx.x * blockDim.x + threadIdx.x; t < TOTAL_F4; t += stride) {
        unsigned spot = t / F4_PER_SPOT;            // magic-mul (const divisor)
        unsigned q    = t - spot * F4_PER_SPOT;     // float4 index within spot
        unsigned b    = spot % B_NUM;

        float h  = height[spot];
        float w  = width[spot];
        float sx = xoff[spot];
        float sy = yoff[spot];

        int n = n_idx[b];
        int f = f_idx[b];
        const float* tl = tlocs + ((unsigned)(n * F_NUM + f)) * 2u;
        sx += tl[0];
        sy += tl[1];

        float w2    = w * w;
        float inv   = __builtin_amdgcn_rcpf(w2);    // ~1 ulp, fine for threshold
        float scale = h * inv * INV_2PI;
        float c     = -HALF_LOG2E * inv;            // exp(-0.5*s/w2) = exp2(s*c)

        unsigned p0 = q * 4u;
        float e[4];
        #pragma unroll
        for (int m = 0; m < 4; ++m) {
            unsigned p = p0 + (unsigned)m;          // pixel index 0..195
            unsigned i = p / D_DIM;                 // magic-mul
            unsigned j = p - i * D_DIM;
            float di = (float)i - sx;
            float dj = (float)j - sy;
            float s  = di * di + dj * dj;
            e[m] = scale * __builtin_amdgcn_exp2f(s * c);
        }
        out[t] = make_float4(e[0], e[1], e[2], e[3]);
    }
}

extern "C" void kernel_launch(void* const* d_in, const int* in_sizes, int n_in,
                              void* d_out, int out_size, void* d_ws, size_t ws_size,
                              hipStream_t stream) {
    const float* height = (const float*)d_in[0];
    const float* width  = (const float*)d_in[1];
    const float* x      = (const float*)d_in[2];
    const float* y      = (const float*)d_in[3];
    const float* tlocs  = (const float*)d_in[4];
    const int*   n_idx  = (const int*)d_in[5];
    const int*   f_idx  = (const int*)d_in[6];
    // d_in[7] is D (==14), baked in at compile time.
    float4* out = (float4*)d_out;

    // Memory-bound: cap grid, grid-stride the rest (G11).
    dim3 grid(2048), block(256);
    hipLaunchKernelGGL(gspot_kernel, grid, block, 0, stream,
                       height, width, x, y, tlocs, n_idx, f_idx, out);
}

// Round 2
// 33.124 us; speedup vs baseline: 1.1802x; 1.1802x over previous
//
#include <hip/hip_runtime.h>

// GaussianSpot: out[k,b,i,j] = h/(2*pi*w^2) * exp(-0.5*((i-sx)^2+(j-sy)^2)/w^2)
// Separable: = [scale*exp2(c*(i-sx)^2)] * [exp2(c*(j-sy)^2)],  c = -0.5*log2(e)/w^2
// K=2, B=100000, D=14 -> 200000 spots x 196 px = 39.2M f32 out (156.8 MB stream write).
// Block = 256 threads, 100 spots: LDS-staged params + 1D exponentials, then a pure
// streaming-store loop (no global loads, no exp) at the HBM write roofline.

#define S_SPOTS 100
#define NBLK    (200000 / S_SPOTS)   // 2000 blocks
#define B_NUM   100000u
#define F_NUM   500
#define D_DIM   14u
#define LSTRIDE 16u                  // padded LDS row stride (shl addressing, bank spread)

__global__ __launch_bounds__(256) void gspot_kernel(
    const float* __restrict__ height,
    const float* __restrict__ width,
    const float* __restrict__ xoff,
    const float* __restrict__ yoff,
    const float* __restrict__ tlocs,   // [N, F, 2]
    const int*   __restrict__ n_idx,   // [B]
    const int*   __restrict__ f_idx,   // [B]
    float4*      __restrict__ out)
{
    __shared__ float sp_sx[S_SPOTS], sp_sy[S_SPOTS], sp_c[S_SPOTS], sp_sc[S_SPOTS];
    __shared__ float ex[S_SPOTS * LSTRIDE];
    __shared__ float ey[S_SPOTS * LSTRIDE];

    const float HALF_LOG2E = 0.7213475204444817f;   // 0.5 * log2(e)
    const float INV_2PI    = 0.15915494309189535f;  // 1 / (2*pi)

    const unsigned tid = threadIdx.x;
    const unsigned spot_base = blockIdx.x * S_SPOTS;

    // ---- Stage A: per-spot params (gather chain done ONCE per spot) ----
    if (tid < S_SPOTS) {
        unsigned spot = spot_base + tid;
        unsigned b    = spot % B_NUM;           // k*B+b layout
        float h  = height[spot];
        float w  = width[spot];
        float sx = xoff[spot];
        float sy = yoff[spot];
        int n = n_idx[b];
        int f = f_idx[b];
        const float* tl = tlocs + ((unsigned)(n * F_NUM + f)) * 2u;
        sx += tl[0];
        sy += tl[1];
        float inv = __builtin_amdgcn_rcpf(w * w);
        sp_sx[tid] = sx;
        sp_sy[tid] = sy;
        sp_c[tid]  = -HALF_LOG2E * inv;
        sp_sc[tid] = h * inv * INV_2PI;
    }
    __syncthreads();

    // ---- Stage B: 1D exponentials, 28 per spot (2800 items / block) ----
    for (unsigned item = tid; item < S_SPOTS * 2u * D_DIM; item += 256u) {
        unsigned sp = item / (2u * D_DIM);      // magic-mul
        unsigned r  = item - sp * (2u * D_DIM);
        float c = sp_c[sp];
        if (r < D_DIM) {
            float d = (float)r - sp_sx[sp];
            ex[sp * LSTRIDE + r] = sp_sc[sp] * __builtin_amdgcn_exp2f(c * d * d);
        } else {
            unsigned j = r - D_DIM;
            float d = (float)j - sp_sy[sp];
            ey[sp * LSTRIDE + j] = __builtin_amdgcn_exp2f(c * d * d);
        }
    }
    __syncthreads();

    // ---- Stage C: pure streaming stores: e[i,j] = ex[i]*ey[j] ----
    float4* outb = out + (size_t)spot_base * 49u;
    for (unsigned idx = tid; idx < S_SPOTS * 49u; idx += 256u) {
        unsigned sp = idx / 49u;                // magic-mul
        unsigned q  = idx - sp * 49u;
        unsigned p0 = q * 4u;
        const float* exb = ex + sp * LSTRIDE;
        const float* eyb = ey + sp * LSTRIDE;
        float e[4];
        #pragma unroll
        for (int m = 0; m < 4; ++m) {
            unsigned p = p0 + (unsigned)m;      // pixel 0..195
            unsigned i = p / D_DIM;             // magic-mul
            unsigned j = p - i * D_DIM;
            e[m] = exb[i] * eyb[j];
        }
        outb[idx] = make_float4(e[0], e[1], e[2], e[3]);
    }
}

extern "C" void kernel_launch(void* const* d_in, const int* in_sizes, int n_in,
                              void* d_out, int out_size, void* d_ws, size_t ws_size,
                              hipStream_t stream) {
    const float* height = (const float*)d_in[0];
    const float* width  = (const float*)d_in[1];
    const float* x      = (const float*)d_in[2];
    const float* y      = (const float*)d_in[3];
    const float* tlocs  = (const float*)d_in[4];
    const int*   n_idx  = (const int*)d_in[5];
    const int*   f_idx  = (const int*)d_in[6];
    float4* out = (float4*)d_out;

    hipLaunchKernelGGL(gspot_kernel, dim3(NBLK), dim3(256), 0, stream,
                       height, width, x, y, tlocs, n_idx, f_idx, out);
}